// Round 13
// baseline (395.357 us; speedup 1.0000x reference)
//
#include <hip/hip_runtime.h>
#include <stdint.h>

using bf16x8 = __attribute__((ext_vector_type(8))) __bf16;
using f32x4  = __attribute__((ext_vector_type(4))) float;

#define AS1 __attribute__((address_space(1)))
#define AS3 __attribute__((address_space(3)))

// ---------------- workspace layout (bytes) ----------------
constexpr size_t OFF_WHH   = 0;                                // [1536][512] bf16
constexpr size_t OFF_WPROJ = OFF_WHH   + (size_t)1536*512*2;   // [512][512] bf16
constexpr size_t OFF_WOUT  = OFF_WPROJ + (size_t)512*512*2;    // [256][512] bf16 (padded)
constexpr size_t OFF_WIH   = OFF_WOUT  + (size_t)256*512*2;    // [1536][256] bf16
constexpr size_t OFF_EMBBF = OFF_WIH   + (size_t)1536*256*2;   // [256][256] bf16 (padded)
constexpr size_t OFF_BHN   = OFF_EMBBF + (size_t)256*256*2;    // [512] f32
constexpr size_t OFF_BPROJ = OFF_BHN   + 2048;
constexpr size_t OFF_BOUT  = OFF_BPROJ + 2048;                 // [256] f32 (padded)
constexpr size_t OFF_BCAT  = OFF_BOUT  + 1024;                 // [1536] f32 gate biases
constexpr size_t OFF_EP    = OFF_BCAT  + 1536*4;               // EP4 [193][512] float4 (r,z,n,-)
constexpr size_t OFF_HS    = OFF_EP    + (size_t)193*512*16;   // [15][8192][512] bf16
constexpr size_t OFF_IMG   = OFF_HS    + (size_t)15*8192*512*2;// [8192][512] bf16
constexpr size_t WS_NEED   = OFF_IMG   + (size_t)8192*512*2;   // ~139 MB

constexpr size_t SLAB = (size_t)8192 * 512;

// ---------------- helpers ----------------
__device__ __forceinline__ short f2bf(float f) {
  union { float f; unsigned u; } v; v.f = f;
  unsigned u = v.u;
  u += 0x7FFFu + ((u >> 16) & 1u);   // RNE
  return (short)(u >> 16);
}
__device__ __forceinline__ float bf2f(short s) {
  union { float f; unsigned u; } v; v.u = ((unsigned)(unsigned short)s) << 16;
  return v.f;
}
__device__ __forceinline__ float sigm(float x) { return 1.f / (1.f + __expf(-x)); }
__device__ __forceinline__ float tanh_fast(float x) {
  x = fminf(fmaxf(x, -15.f), 15.f);
  float e = __expf(-2.f * x);
  return (1.f - e) / (1.f + e);
}

// Stage ROWS x 64(bf16) tile: linear LDS dest, XOR-swizzled per-lane global source
// (rule #21: linear dest + inverse-swz source + swz on read).
template<int ROWS, int WAVES>
__device__ __forceinline__ void stage_tile(const short* __restrict__ src, size_t row0,
                                           int stride, int k0, char* lds, int tid) {
  const int w = tid >> 6;
  const int lane = tid & 63;
#pragma unroll
  for (int s = 0; s < ROWS / (8 * WAVES); ++s) {
    const int rowbase = s * (8 * WAVES) + w * 8;   // wave-uniform
    const int row = rowbase + (lane >> 3);
    const int colE = ((lane & 7) ^ (row & 7)) * 8; // pre-swizzled source column
    const short* g = src + (row0 + (size_t)row) * (size_t)stride + k0 + colE;
    __builtin_amdgcn_global_load_lds((const AS1 int*)g, (AS3 int*)(lds + rowbase * 128),
                                     16, 0, 0);
  }
}

// Read a 16x32 MFMA fragment (8 bf16/lane) with the matching XOR swizzle.
__device__ __forceinline__ bf16x8 read_frag(const char* lds, int row, int ks, int lane) {
  const int kb = ks * 64 + ((lane >> 4) << 4);
  return *(const bf16x8*)(lds + row * 128 + (kb ^ ((row & 7) << 4)));
}

// ---------------- prep: pack weights/biases (bf16) ----------------
__global__ void prep_kernel(const float* __restrict__ W_proj, const float* __restrict__ b_proj,
                            const float* __restrict__ W_hh, const float* __restrict__ b_hh,
                            const float* __restrict__ W_ih, const float* __restrict__ b_ih,
                            const float* __restrict__ emb,
                            const float* __restrict__ W_out, const float* __restrict__ b_out,
                            short* __restrict__ whh, short* __restrict__ wproj,
                            short* __restrict__ wout, short* __restrict__ wih,
                            short* __restrict__ embbf,
                            float* __restrict__ bhn, float* __restrict__ bproj,
                            float* __restrict__ bout, float* __restrict__ bcat) {
  const int total = 1536*512 + 512*512 + 256*512 + 1536*256 + 256*256 + 512 + 512 + 256 + 1536;
  const int stride = gridDim.x * blockDim.x;
  for (int i = blockIdx.x * blockDim.x + threadIdx.x; i < total; i += stride) {
    int j = i;
    if (j < 1536*512) { whh[j] = f2bf(W_hh[j]); continue; }
    j -= 1536*512;
    if (j < 512*512) { wproj[j] = f2bf(W_proj[j]); continue; }
    j -= 512*512;
    if (j < 256*512) {
      int r = j / 512, c = j % 512;
      wout[j] = f2bf(r < 193 ? W_out[r*512 + c] : 0.f);
      continue;
    }
    j -= 256*512;
    if (j < 1536*256) { wih[j] = f2bf(W_ih[j]); continue; }
    j -= 1536*256;
    if (j < 256*256) {
      int r = j >> 8, c = j & 255;
      embbf[j] = f2bf(r < 193 ? emb[r*256 + c] : 0.f);
      continue;
    }
    j -= 256*256;
    if (j < 512) { bhn[j] = b_hh[1024 + j]; continue; }
    j -= 512;
    if (j < 512) { bproj[j] = b_proj[j]; continue; }
    j -= 512;
    if (j < 256) { bout[j] = (j < 193) ? b_out[j] : 0.f; continue; }
    j -= 256;
    bcat[j] = b_ih[j] + (j < 1024 ? b_hh[j] : 0.f);
  }
}

// ---------------- img -> bf16 ----------------
__global__ void imgcvt_kernel(const float* __restrict__ img, short* __restrict__ imgbf) {
  const int i = blockIdx.x * blockDim.x + threadIdx.x;  // 8192*128 groups of 4
  const float4 v = *(const float4*)(img + (size_t)i * 4);
  short4 o; o.x = f2bf(v.x); o.y = f2bf(v.y); o.z = f2bf(v.z); o.w = f2bf(v.w);
  *(short4*)(imgbf + (size_t)i * 4) = o;
}

// ---------------- EP via MFMA: EP[256pad x 1536] = embbf @ wih^T + bcat ----------------
// 64M x 256N tile, K=256 (4 iters), grid (4,6). Writes component c>>9 of ep4[v][c&511].
__global__ __launch_bounds__(256, 4)
void embproj_mfma_kernel(const short* __restrict__ embbf, const short* __restrict__ wih,
                         const float* __restrict__ bcat, float* __restrict__ ep) {
  __shared__ __align__(16) char smem[40960];   // A 8K + B 32K
  char* ldsA = smem;
  char* ldsB = smem + 8192;
  const int tid = threadIdx.x;
  const int lane = tid & 63;
  const int w = tid >> 6;
  const int wr = w >> 1, wc = w & 1;   // wave-tile 32M x 128N
  const unsigned m0 = blockIdx.x * 64;
  const int j0 = blockIdx.y * 256;

  f32x4 acc[2][8];
#pragma unroll
  for (int a = 0; a < 2; ++a)
#pragma unroll
    for (int b = 0; b < 8; ++b) acc[a][b] = f32x4{0.f, 0.f, 0.f, 0.f};

  for (int it = 0; it < 4; ++it) {
    const int k0 = it * 64;
    __syncthreads();
    stage_tile<64, 4>(embbf, m0, 256, k0, ldsA, tid);
    stage_tile<256, 4>(wih, (size_t)j0, 256, k0, ldsB, tid);
    __syncthreads();
#pragma unroll
    for (int ks = 0; ks < 2; ++ks) {
      bf16x8 af[2];
#pragma unroll
      for (int mi = 0; mi < 2; ++mi)
        af[mi] = read_frag(ldsA, wr*32 + mi*16 + (lane & 15), ks, lane);
#pragma unroll
      for (int ji = 0; ji < 8; ++ji) {
        bf16x8 bfm = read_frag(ldsB, wc*128 + ji*16 + (lane & 15), ks, lane);
#pragma unroll
        for (int mi = 0; mi < 2; ++mi)
          acc[mi][ji] = __builtin_amdgcn_mfma_f32_16x16x32_bf16(af[mi], bfm, acc[mi][ji], 0, 0, 0);
      }
    }
  }
#pragma unroll
  for (int ji = 0; ji < 8; ++ji) {
    const int c = j0 + wc*128 + ji*16 + (lane & 15);
    const int gate = c >> 9, jj = c & 511;
    const float bc = bcat[c];
#pragma unroll
    for (int mi = 0; mi < 2; ++mi) {
#pragma unroll
      for (int i = 0; i < 4; ++i) {
        const unsigned v = m0 + wr*32 + mi*16 + ((lane >> 4) * 4) + i;
        if (v < 193) ep[((size_t)v * 512 + jj) * 4 + gate] = acc[mi][ji][i] + bc;
      }
    }
  }
}

// ---------------- GEMM, 4 waves (2x2), 64M x 256N tile, K=512, 4 blocks/CU ----------------
// MODE 0: h0 projection. A=imgbf (linear rows), write bf16 hs[0][m][j].
// MODE 1: vocab out. M is b-major (m = b*14 + t); A row = hs1[t*8192 + b];
//         writes f32 out[m*193 + j] (fully contiguous across the tile).
template<int MODE>
__global__ __launch_bounds__(256, 4)
void gemm_kernel(const short* __restrict__ A, const short* __restrict__ Bw,
                 const float* __restrict__ bias, float* __restrict__ out_f,
                 short* __restrict__ out_bf) {
  __shared__ __align__(16) char smem[40960];   // A 8K + B 32K  (x4 blocks/CU = 160K)
  char* ldsA = smem;
  char* ldsB = smem + 8192;
  const int tid = threadIdx.x;
  const int lane = tid & 63;
  const int w = tid >> 6;
  const int wr = w >> 1, wc = w & 1;   // 2x2 wave grid, wave-tile 32M x 128N
  const unsigned m0 = blockIdx.x * 64;
  const int j0 = blockIdx.y * 256;

  f32x4 acc[2][8];
#pragma unroll
  for (int a = 0; a < 2; ++a)
#pragma unroll
    for (int b = 0; b < 8; ++b) acc[a][b] = f32x4{0.f, 0.f, 0.f, 0.f};

  for (int it = 0; it < 8; ++it) {
    const int k0 = it * 64;
    __syncthreads();
    if (MODE == 0) {
      stage_tile<64, 4>(A, m0, 512, k0, ldsA, tid);
    } else {
      // b-major A rows: row r -> m=m0+r -> (b=m/14, t=m%14) -> hs1[t*8192+b]
#pragma unroll
      for (int s = 0; s < 2; ++s) {
        const int rowbase = s * 32 + w * 8;
        const int row = rowbase + (lane >> 3);
        const unsigned m = m0 + row;
        const unsigned b = m / 14u, t = m - b * 14u;
        const int colE = ((lane & 7) ^ (row & 7)) * 8;
        const short* g = A + ((size_t)t * 8192 + b) * 512 + k0 + colE;
        __builtin_amdgcn_global_load_lds((const AS1 int*)g, (AS3 int*)(ldsA + rowbase * 128),
                                         16, 0, 0);
      }
    }
    stage_tile<256, 4>(Bw, (size_t)j0, 512, k0, ldsB, tid);
    __syncthreads();
#pragma unroll
    for (int ks = 0; ks < 2; ++ks) {
      bf16x8 af[2];
#pragma unroll
      for (int mi = 0; mi < 2; ++mi)
        af[mi] = read_frag(ldsA, wr*32 + mi*16 + (lane & 15), ks, lane);
#pragma unroll
      for (int ji = 0; ji < 8; ++ji) {
        bf16x8 bfm = read_frag(ldsB, wc*128 + ji*16 + (lane & 15), ks, lane);
#pragma unroll
        for (int mi = 0; mi < 2; ++mi)
          acc[mi][ji] = __builtin_amdgcn_mfma_f32_16x16x32_bf16(af[mi], bfm, acc[mi][ji], 0, 0, 0);
      }
    }
  }
#pragma unroll
  for (int ji = 0; ji < 8; ++ji) {
    const int j = j0 + wc*128 + ji*16 + (lane & 15);
    const float bj = bias[j];
#pragma unroll
    for (int mi = 0; mi < 2; ++mi) {
#pragma unroll
      for (int i = 0; i < 4; ++i) {
        const size_t m = m0 + wr*32 + mi*16 + ((lane >> 4) * 4) + i;
        const float v = acc[mi][ji][i] + bj;
        if (MODE == 0) {
          out_bf[m * 512 + j] = f2bf(v);
        } else {
          if (j < 193) out_f[m * 193 + j] = v;   // m is b-major bt index: contiguous
        }
      }
    }
  }
}

// ---------------- fused GRU step: gh = h @ W_hh^T, 64M x 64N x BK=64, 4 blocks/CU ----
// 1024 blocks (each XCD: 16 m-tiles x 8 j-tiles), 256 thr (2x2 waves, wave-tile 32x32),
// LDS 32 KB (A 8K + B 24K) -> 4 blocks/CU = 128 KB, 16 waves/CU.
// Epilogue: r=sigm(acc_r+ep.x); z=sigm(acc_z+ep.y); n=tanh(ep.z + r*(acc_hn+bhn));
//           h' = (1-z)n + z h  (h re-read from L2-hot Hbf slab).
__global__ __launch_bounds__(256, 4)
void gate_kernel(const short* __restrict__ Hbf, const short* __restrict__ whh,
                 const int* __restrict__ text, const int t,
                 const float4* __restrict__ ep4, const float* __restrict__ bhn,
                 short* __restrict__ hs_out) {
  __shared__ __align__(16) char smem[32768];   // A 8K + B(3 gates) 24K
  char* ldsA = smem;
  char* ldsB = smem + 8192;
  const int tid = threadIdx.x;
  const int lane = tid & 63;
  const int w = tid >> 6;
  const int wr = w >> 1, wc = w & 1;   // wave-tile 32M x 32N
  const unsigned raw = blockIdx.x;
  const unsigned xcd = raw & 7, slot = raw >> 3;           // 1024 blocks: slot 0..127
  const unsigned mt = xcd * 16 + (slot & 15), jt = slot >> 4;
  const size_t m0 = (size_t)mt * 64;
  const int j0 = jt * 64;

  // prefetch tokens (gather latency hides under the K-loop)
  int toks[2][4];
#pragma unroll
  for (int mi = 0; mi < 2; ++mi)
#pragma unroll
    for (int i = 0; i < 4; ++i) {
      const size_t m = m0 + wr*32 + mi*16 + ((lane >> 4) * 4) + i;
      toks[mi][i] = text[m * 15 + t];
    }

  f32x4 acc_r[2][2], acc_z[2][2], acc_hn[2][2];
#pragma unroll
  for (int a = 0; a < 2; ++a)
#pragma unroll
    for (int b = 0; b < 2; ++b) {
      acc_r[a][b] = f32x4{0.f, 0.f, 0.f, 0.f};
      acc_z[a][b] = f32x4{0.f, 0.f, 0.f, 0.f};
      acc_hn[a][b] = f32x4{0.f, 0.f, 0.f, 0.f};
    }

  for (int it = 0; it < 8; ++it) {
    const int k0 = it * 64;
    __syncthreads();
    stage_tile<64, 4>(Hbf, m0, 512, k0, ldsA, tid);          // 2 loads/thread
#pragma unroll
    for (int g = 0; g < 3; ++g)                              // 6 loads/thread
      stage_tile<64, 4>(whh, (size_t)(g * 512 + j0), 512, k0, ldsB + g * 8192, tid);
    __syncthreads();
#pragma unroll
    for (int ks = 0; ks < 2; ++ks) {
      bf16x8 af[2];
#pragma unroll
      for (int mi = 0; mi < 2; ++mi)
        af[mi] = read_frag(ldsA, wr*32 + mi*16 + (lane & 15), ks, lane);
#pragma unroll
      for (int ji = 0; ji < 2; ++ji) {
        const int nb = wc*32 + ji*16 + (lane & 15);
        bf16x8 b_r = read_frag(ldsB,         nb, ks, lane);
        bf16x8 b_z = read_frag(ldsB + 8192,  nb, ks, lane);
        bf16x8 b_n = read_frag(ldsB + 16384, nb, ks, lane);
#pragma unroll
        for (int mi = 0; mi < 2; ++mi) {
          acc_r[mi][ji]  = __builtin_amdgcn_mfma_f32_16x16x32_bf16(af[mi], b_r, acc_r[mi][ji], 0, 0, 0);
          acc_z[mi][ji]  = __builtin_amdgcn_mfma_f32_16x16x32_bf16(af[mi], b_z, acc_z[mi][ji], 0, 0, 0);
          acc_hn[mi][ji] = __builtin_amdgcn_mfma_f32_16x16x32_bf16(af[mi], b_n, acc_hn[mi][ji], 0, 0, 0);
        }
      }
    }
  }
  // epilogue: gather EP4[token] + gate math + h update
#pragma unroll
  for (int ji = 0; ji < 2; ++ji) {
    const int j = j0 + wc*32 + ji*16 + (lane & 15);
    const float vbhn = bhn[j];
#pragma unroll
    for (int mi = 0; mi < 2; ++mi) {
#pragma unroll
      for (int i = 0; i < 4; ++i) {
        const size_t m = m0 + wr*32 + mi*16 + ((lane >> 4) * 4) + i;
        const float4 e = ep4[(size_t)toks[mi][i] * 512 + j];
        const float r = sigm(acc_r[mi][ji][i] + e.x);
        const float z = sigm(acc_z[mi][ji][i] + e.y);
        const float n = tanh_fast(e.z + r * (acc_hn[mi][ji][i] + vbhn));
        const float hold = bf2f(Hbf[m * 512 + j]);
        hs_out[m * 512 + j] = f2bf((1.f - z) * n + z * hold);
      }
    }
  }
}

// ---------------- launch ----------------
extern "C" void kernel_launch(void* const* d_in, const int* in_sizes, int n_in,
                              void* d_out, int out_size, void* d_ws, size_t ws_size,
                              hipStream_t stream) {
  (void)in_sizes; (void)n_in; (void)out_size;
  if (ws_size < WS_NEED) return;

  const float* img    = (const float*)d_in[0];
  const int*   text   = (const int*)  d_in[1];
  const float* emb    = (const float*)d_in[2];
  const float* W_proj = (const float*)d_in[3];
  const float* b_proj = (const float*)d_in[4];
  const float* W_ih   = (const float*)d_in[5];
  const float* W_hh   = (const float*)d_in[6];
  const float* b_ih   = (const float*)d_in[7];
  const float* b_hh   = (const float*)d_in[8];
  const float* W_out  = (const float*)d_in[9];
  const float* b_out  = (const float*)d_in[10];
  float* out = (float*)d_out;
  char* ws = (char*)d_ws;

  short* whh   = (short*)(ws + OFF_WHH);
  short* wproj = (short*)(ws + OFF_WPROJ);
  short* wout  = (short*)(ws + OFF_WOUT);
  short* wih   = (short*)(ws + OFF_WIH);
  short* embbf = (short*)(ws + OFF_EMBBF);
  float* bhn   = (float*)(ws + OFF_BHN);
  float* bproj = (float*)(ws + OFF_BPROJ);
  float* bout  = (float*)(ws + OFF_BOUT);
  float* bcat  = (float*)(ws + OFF_BCAT);
  float* epf   = (float*)(ws + OFF_EP);
  float4* ep4  = (float4*)(ws + OFF_EP);
  short* hs    = (short*)(ws + OFF_HS);
  short* imgbf = (short*)(ws + OFF_IMG);

  prep_kernel<<<512, 256, 0, stream>>>(W_proj, b_proj, W_hh, b_hh, W_ih, b_ih, emb,
                                       W_out, b_out,
                                       whh, wproj, wout, wih, embbf,
                                       bhn, bproj, bout, bcat);
  imgcvt_kernel<<<4096, 256, 0, stream>>>(img, imgbf);

  // EP = emb @ W_ih^T + biases, via MFMA
  embproj_mfma_kernel<<<dim3(4, 6), 256, 0, stream>>>(embbf, wih, bcat, epf);

  // h0 = img @ W_proj^T + b_proj  -> hs[0] (bf16); 64M x 256N tiles
  gemm_kernel<0><<<dim3(128, 2), 256, 0, stream>>>(imgbf, wproj, bproj, nullptr, hs);

  for (int t = 0; t < 14; ++t) {
    const short* Hb = hs + (size_t)t * SLAB;
    short* Ho       = hs + (size_t)(t + 1) * SLAB;
    gate_kernel<<<1024, 256, 0, stream>>>(Hb, whh, text, t, ep4, bhn, Ho);
  }

  // preds: b-major M (m = b*14+t), A = hs slab starting at t=1; 64M tiles
  gemm_kernel<1><<<dim3(1792, 1), 256, 0, stream>>>(hs + (size_t)8192 * 512, wout, bout,
                                                    out, nullptr);
}

// Round 14
// 376.961 us; speedup vs baseline: 1.0488x; 1.0488x over previous
//
#include <hip/hip_runtime.h>
#include <stdint.h>

using bf16x8 = __attribute__((ext_vector_type(8))) __bf16;
using f32x4  = __attribute__((ext_vector_type(4))) float;

#define AS1 __attribute__((address_space(1)))
#define AS3 __attribute__((address_space(3)))

// ---------------- workspace layout (bytes) ----------------
constexpr size_t OFF_WHH   = 0;                                // [1536][512] bf16
constexpr size_t OFF_WPROJ = OFF_WHH   + (size_t)1536*512*2;   // [512][512] bf16
constexpr size_t OFF_WOUT  = OFF_WPROJ + (size_t)512*512*2;    // [256][512] bf16 (padded)
constexpr size_t OFF_WIH   = OFF_WOUT  + (size_t)256*512*2;    // [1536][256] bf16
constexpr size_t OFF_EMBBF = OFF_WIH   + (size_t)1536*256*2;   // [256][256] bf16 (padded)
constexpr size_t OFF_BHN   = OFF_EMBBF + (size_t)256*256*2;    // [512] f32
constexpr size_t OFF_BPROJ = OFF_BHN   + 2048;
constexpr size_t OFF_BOUT  = OFF_BPROJ + 2048;                 // [256] f32 (padded)
constexpr size_t OFF_BCAT  = OFF_BOUT  + 1024;                 // [1536] f32 gate biases
constexpr size_t OFF_EP    = OFF_BCAT  + 1536*4;               // EP4 [193][512] float4 (r,z,n,-)
constexpr size_t OFF_HS    = OFF_EP    + (size_t)193*512*16;   // [15][8192][512] bf16
constexpr size_t OFF_IMG   = OFF_HS    + (size_t)15*8192*512*2;// [8192][512] bf16
constexpr size_t WS_NEED   = OFF_IMG   + (size_t)8192*512*2;   // ~139 MB

constexpr size_t SLAB = (size_t)8192 * 512;

// ---------------- helpers ----------------
__device__ __forceinline__ short f2bf(float f) {
  union { float f; unsigned u; } v; v.f = f;
  unsigned u = v.u;
  u += 0x7FFFu + ((u >> 16) & 1u);   // RNE
  return (short)(u >> 16);
}
__device__ __forceinline__ float bf2f(short s) {
  union { float f; unsigned u; } v; v.u = ((unsigned)(unsigned short)s) << 16;
  return v.f;
}
__device__ __forceinline__ float sigm(float x) { return 1.f / (1.f + __expf(-x)); }
__device__ __forceinline__ float tanh_fast(float x) {
  x = fminf(fmaxf(x, -15.f), 15.f);
  float e = __expf(-2.f * x);
  return (1.f - e) / (1.f + e);
}

// Stage ROWS x 64(bf16) tile: linear LDS dest, XOR-swizzled per-lane global source
// (rule #21: linear dest + inverse-swz source + swz on read).
template<int ROWS, int WAVES>
__device__ __forceinline__ void stage_tile(const short* __restrict__ src, size_t row0,
                                           int stride, int k0, char* lds, int tid) {
  const int w = tid >> 6;
  const int lane = tid & 63;
#pragma unroll
  for (int s = 0; s < ROWS / (8 * WAVES); ++s) {
    const int rowbase = s * (8 * WAVES) + w * 8;   // wave-uniform
    const int row = rowbase + (lane >> 3);
    const int colE = ((lane & 7) ^ (row & 7)) * 8; // pre-swizzled source column
    const short* g = src + (row0 + (size_t)row) * (size_t)stride + k0 + colE;
    __builtin_amdgcn_global_load_lds((const AS1 int*)g, (AS3 int*)(lds + rowbase * 128),
                                     16, 0, 0);
  }
}

// Read a 16x32 MFMA fragment (8 bf16/lane) with the matching XOR swizzle.
__device__ __forceinline__ bf16x8 read_frag(const char* lds, int row, int ks, int lane) {
  const int kb = ks * 64 + ((lane >> 4) << 4);
  return *(const bf16x8*)(lds + row * 128 + (kb ^ ((row & 7) << 4)));
}

// ---------------- prep: pack weights/biases (bf16) ----------------
__global__ void prep_kernel(const float* __restrict__ W_proj, const float* __restrict__ b_proj,
                            const float* __restrict__ W_hh, const float* __restrict__ b_hh,
                            const float* __restrict__ W_ih, const float* __restrict__ b_ih,
                            const float* __restrict__ emb,
                            const float* __restrict__ W_out, const float* __restrict__ b_out,
                            short* __restrict__ whh, short* __restrict__ wproj,
                            short* __restrict__ wout, short* __restrict__ wih,
                            short* __restrict__ embbf,
                            float* __restrict__ bhn, float* __restrict__ bproj,
                            float* __restrict__ bout, float* __restrict__ bcat) {
  const int total = 1536*512 + 512*512 + 256*512 + 1536*256 + 256*256 + 512 + 512 + 256 + 1536;
  const int stride = gridDim.x * blockDim.x;
  for (int i = blockIdx.x * blockDim.x + threadIdx.x; i < total; i += stride) {
    int j = i;
    if (j < 1536*512) { whh[j] = f2bf(W_hh[j]); continue; }
    j -= 1536*512;
    if (j < 512*512) { wproj[j] = f2bf(W_proj[j]); continue; }
    j -= 512*512;
    if (j < 256*512) {
      int r = j / 512, c = j % 512;
      wout[j] = f2bf(r < 193 ? W_out[r*512 + c] : 0.f);
      continue;
    }
    j -= 256*512;
    if (j < 1536*256) { wih[j] = f2bf(W_ih[j]); continue; }
    j -= 1536*256;
    if (j < 256*256) {
      int r = j >> 8, c = j & 255;
      embbf[j] = f2bf(r < 193 ? emb[r*256 + c] : 0.f);
      continue;
    }
    j -= 256*256;
    if (j < 512) { bhn[j] = b_hh[1024 + j]; continue; }
    j -= 512;
    if (j < 512) { bproj[j] = b_proj[j]; continue; }
    j -= 512;
    if (j < 256) { bout[j] = (j < 193) ? b_out[j] : 0.f; continue; }
    j -= 256;
    bcat[j] = b_ih[j] + (j < 1024 ? b_hh[j] : 0.f);
  }
}

// ---------------- img -> bf16 ----------------
__global__ void imgcvt_kernel(const float* __restrict__ img, short* __restrict__ imgbf) {
  const int i = blockIdx.x * blockDim.x + threadIdx.x;  // 8192*128 groups of 4
  const float4 v = *(const float4*)(img + (size_t)i * 4);
  short4 o; o.x = f2bf(v.x); o.y = f2bf(v.y); o.z = f2bf(v.z); o.w = f2bf(v.w);
  *(short4*)(imgbf + (size_t)i * 4) = o;
}

// ---------------- EP via MFMA: EP[256pad x 1536] = embbf @ wih^T + bcat ----------------
// 64M x 256N tile, K=256 (4 iters), grid (4,6). Writes component c>>9 of ep4[v][c&511].
__global__ __launch_bounds__(256, 4)
void embproj_mfma_kernel(const short* __restrict__ embbf, const short* __restrict__ wih,
                         const float* __restrict__ bcat, float* __restrict__ ep) {
  __shared__ __align__(16) char smem[40960];   // A 8K + B 32K
  char* ldsA = smem;
  char* ldsB = smem + 8192;
  const int tid = threadIdx.x;
  const int lane = tid & 63;
  const int w = tid >> 6;
  const int wr = w >> 1, wc = w & 1;   // wave-tile 32M x 128N
  const unsigned m0 = blockIdx.x * 64;
  const int j0 = blockIdx.y * 256;

  f32x4 acc[2][8];
#pragma unroll
  for (int a = 0; a < 2; ++a)
#pragma unroll
    for (int b = 0; b < 8; ++b) acc[a][b] = f32x4{0.f, 0.f, 0.f, 0.f};

  for (int it = 0; it < 4; ++it) {
    const int k0 = it * 64;
    __syncthreads();
    stage_tile<64, 4>(embbf, m0, 256, k0, ldsA, tid);
    stage_tile<256, 4>(wih, (size_t)j0, 256, k0, ldsB, tid);
    __syncthreads();
#pragma unroll
    for (int ks = 0; ks < 2; ++ks) {
      bf16x8 af[2];
#pragma unroll
      for (int mi = 0; mi < 2; ++mi)
        af[mi] = read_frag(ldsA, wr*32 + mi*16 + (lane & 15), ks, lane);
#pragma unroll
      for (int ji = 0; ji < 8; ++ji) {
        bf16x8 bfm = read_frag(ldsB, wc*128 + ji*16 + (lane & 15), ks, lane);
#pragma unroll
        for (int mi = 0; mi < 2; ++mi)
          acc[mi][ji] = __builtin_amdgcn_mfma_f32_16x16x32_bf16(af[mi], bfm, acc[mi][ji], 0, 0, 0);
      }
    }
  }
#pragma unroll
  for (int ji = 0; ji < 8; ++ji) {
    const int c = j0 + wc*128 + ji*16 + (lane & 15);
    const int gate = c >> 9, jj = c & 511;
    const float bc = bcat[c];
#pragma unroll
    for (int mi = 0; mi < 2; ++mi) {
#pragma unroll
      for (int i = 0; i < 4; ++i) {
        const unsigned v = m0 + wr*32 + mi*16 + ((lane >> 4) * 4) + i;
        if (v < 193) ep[((size_t)v * 512 + jj) * 4 + gate] = acc[mi][ji][i] + bc;
      }
    }
  }
}

// ---------------- GEMM, 4 waves (2x2), 64M x 256N tile, K=512, 4 blocks/CU ----------------
// MODE 0: h0 projection. A=imgbf (linear rows), write bf16 hs[0][m][j].
// MODE 1: vocab out. M is b-major (m = b*14 + t); A row = hs1[t*8192 + b];
//         writes f32 out[m*193 + j] (fully contiguous across the tile).
template<int MODE>
__global__ __launch_bounds__(256, 4)
void gemm_kernel(const short* __restrict__ A, const short* __restrict__ Bw,
                 const float* __restrict__ bias, float* __restrict__ out_f,
                 short* __restrict__ out_bf) {
  __shared__ __align__(16) char smem[40960];   // A 8K + B 32K  (x4 blocks/CU = 160K)
  char* ldsA = smem;
  char* ldsB = smem + 8192;
  const int tid = threadIdx.x;
  const int lane = tid & 63;
  const int w = tid >> 6;
  const int wr = w >> 1, wc = w & 1;   // 2x2 wave grid, wave-tile 32M x 128N
  const unsigned m0 = blockIdx.x * 64;
  const int j0 = blockIdx.y * 256;

  f32x4 acc[2][8];
#pragma unroll
  for (int a = 0; a < 2; ++a)
#pragma unroll
    for (int b = 0; b < 8; ++b) acc[a][b] = f32x4{0.f, 0.f, 0.f, 0.f};

  for (int it = 0; it < 8; ++it) {
    const int k0 = it * 64;
    __syncthreads();
    if (MODE == 0) {
      stage_tile<64, 4>(A, m0, 512, k0, ldsA, tid);
    } else {
      // b-major A rows: row r -> m=m0+r -> (b=m/14, t=m%14) -> hs1[t*8192+b]
#pragma unroll
      for (int s = 0; s < 2; ++s) {
        const int rowbase = s * 32 + w * 8;
        const int row = rowbase + (lane >> 3);
        const unsigned m = m0 + row;
        const unsigned b = m / 14u, t = m - b * 14u;
        const int colE = ((lane & 7) ^ (row & 7)) * 8;
        const short* g = A + ((size_t)t * 8192 + b) * 512 + k0 + colE;
        __builtin_amdgcn_global_load_lds((const AS1 int*)g, (AS3 int*)(ldsA + rowbase * 128),
                                         16, 0, 0);
      }
    }
    stage_tile<256, 4>(Bw, (size_t)j0, 512, k0, ldsB, tid);
    __syncthreads();
#pragma unroll
    for (int ks = 0; ks < 2; ++ks) {
      bf16x8 af[2];
#pragma unroll
      for (int mi = 0; mi < 2; ++mi)
        af[mi] = read_frag(ldsA, wr*32 + mi*16 + (lane & 15), ks, lane);
#pragma unroll
      for (int ji = 0; ji < 8; ++ji) {
        bf16x8 bfm = read_frag(ldsB, wc*128 + ji*16 + (lane & 15), ks, lane);
#pragma unroll
        for (int mi = 0; mi < 2; ++mi)
          acc[mi][ji] = __builtin_amdgcn_mfma_f32_16x16x32_bf16(af[mi], bfm, acc[mi][ji], 0, 0, 0);
      }
    }
  }
#pragma unroll
  for (int ji = 0; ji < 8; ++ji) {
    const int j = j0 + wc*128 + ji*16 + (lane & 15);
    const float bj = bias[j];
#pragma unroll
    for (int mi = 0; mi < 2; ++mi) {
#pragma unroll
      for (int i = 0; i < 4; ++i) {
        const size_t m = m0 + wr*32 + mi*16 + ((lane >> 4) * 4) + i;
        const float v = acc[mi][ji][i] + bj;
        if (MODE == 0) {
          out_bf[m * 512 + j] = f2bf(v);
        } else {
          if (j < 193) out_f[m * 193 + j] = v;   // m is b-major bt index: contiguous
        }
      }
    }
  }
}

// ---------------- fused GRU step: gh = h @ W_hh^T, BK=128, XCD-swizzled 1-D grid ----
// Grid 512 blocks; decode so each XCD (id&7, round-robin dispatch) owns
// 8 consecutive m-tiles x all 8 j-tiles -> per-XCD L2 working set = 1MB h + 1.5MB whh.
// LDS: A0|A1 (16K each) + B0|B1 (24K each) = 80K; 2 blocks/CU = 160K exact.
__global__ __launch_bounds__(256, 2)
void gate_kernel(const short* __restrict__ Hbf, const short* __restrict__ whh,
                 const int* __restrict__ text, const int t,
                 const float4* __restrict__ ep4, const float* __restrict__ bhn,
                 short* __restrict__ hs_out) {
  __shared__ __align__(16) char smem[81920];
  char* ldsA0 = smem;                // [128][64] k-half 0
  char* ldsA1 = smem + 16384;        // [128][64] k-half 1
  char* ldsB0 = smem + 32768;        // 3 x [64][64] k-half 0
  char* ldsB1 = smem + 57344;        // 3 x [64][64] k-half 1
  const int tid = threadIdx.x;
  const int lane = tid & 63;
  const int w = tid >> 6;
  const int wr = w >> 1, wc = w & 1;   // wave-tile 64M x 32N
  const unsigned raw = blockIdx.x;
  const unsigned xcd = raw & 7, slot = raw >> 3;
  const unsigned mt = xcd * 8 + (slot & 7), jt = slot >> 3;
  const size_t m0 = (size_t)mt * 128;
  const int j0 = jt * 64;

  // prefetch tokens (gather latency hides under the K-loop)
  int toks[4][4];
#pragma unroll
  for (int mi = 0; mi < 4; ++mi)
#pragma unroll
    for (int i = 0; i < 4; ++i) {
      const size_t m = m0 + wr*64 + mi*16 + ((lane >> 4) * 4) + i;
      toks[mi][i] = text[m * 15 + t];
    }

  f32x4 acc_r[4][2], acc_z[4][2], acc_hn[4][2];
#pragma unroll
  for (int a = 0; a < 4; ++a)
#pragma unroll
    for (int b = 0; b < 2; ++b) {
      acc_r[a][b] = f32x4{0.f, 0.f, 0.f, 0.f};
      acc_z[a][b] = f32x4{0.f, 0.f, 0.f, 0.f};
      acc_hn[a][b] = f32x4{0.f, 0.f, 0.f, 0.f};
    }

  for (int it = 0; it < 4; ++it) {
    const int k0 = it * 128;
    __syncthreads();
    stage_tile<128, 4>(Hbf, m0, 512, k0, ldsA0, tid);
    stage_tile<128, 4>(Hbf, m0, 512, k0 + 64, ldsA1, tid);
#pragma unroll
    for (int g = 0; g < 3; ++g) {
      stage_tile<64, 4>(whh, (size_t)(g * 512 + j0), 512, k0,      ldsB0 + g * 8192, tid);
      stage_tile<64, 4>(whh, (size_t)(g * 512 + j0), 512, k0 + 64, ldsB1 + g * 8192, tid);
    }
    __syncthreads();
#pragma unroll
    for (int half = 0; half < 2; ++half) {
      const char* lA = half ? ldsA1 : ldsA0;
      const char* lB = half ? ldsB1 : ldsB0;
#pragma unroll
      for (int ks = 0; ks < 2; ++ks) {
        bf16x8 af[4];
#pragma unroll
        for (int mi = 0; mi < 4; ++mi)
          af[mi] = read_frag(lA, wr*64 + mi*16 + (lane & 15), ks, lane);
#pragma unroll
        for (int ji = 0; ji < 2; ++ji) {
          const int nb = wc*32 + ji*16 + (lane & 15);
          bf16x8 b_r = read_frag(lB,         nb, ks, lane);
          bf16x8 b_z = read_frag(lB + 8192,  nb, ks, lane);
          bf16x8 b_n = read_frag(lB + 16384, nb, ks, lane);
#pragma unroll
          for (int mi = 0; mi < 4; ++mi) {
            acc_r[mi][ji]  = __builtin_amdgcn_mfma_f32_16x16x32_bf16(af[mi], b_r, acc_r[mi][ji], 0, 0, 0);
            acc_z[mi][ji]  = __builtin_amdgcn_mfma_f32_16x16x32_bf16(af[mi], b_z, acc_z[mi][ji], 0, 0, 0);
            acc_hn[mi][ji] = __builtin_amdgcn_mfma_f32_16x16x32_bf16(af[mi], b_n, acc_hn[mi][ji], 0, 0, 0);
          }
        }
      }
    }
  }
  // epilogue: gather EP4[token] + gate math + h update
#pragma unroll
  for (int ji = 0; ji < 2; ++ji) {
    const int j = j0 + wc*32 + ji*16 + (lane & 15);
    const float vbhn = bhn[j];
#pragma unroll
    for (int mi = 0; mi < 4; ++mi) {
#pragma unroll
      for (int i = 0; i < 4; ++i) {
        const size_t m = m0 + wr*64 + mi*16 + ((lane >> 4) * 4) + i;
        const float4 e = ep4[(size_t)toks[mi][i] * 512 + j];
        const float r = sigm(acc_r[mi][ji][i] + e.x);
        const float z = sigm(acc_z[mi][ji][i] + e.y);
        const float n = tanh_fast(e.z + r * (acc_hn[mi][ji][i] + vbhn));
        const float hold = bf2f(Hbf[m * 512 + j]);
        hs_out[m * 512 + j] = f2bf((1.f - z) * n + z * hold);
      }
    }
  }
}

// ---------------- launch ----------------
extern "C" void kernel_launch(void* const* d_in, const int* in_sizes, int n_in,
                              void* d_out, int out_size, void* d_ws, size_t ws_size,
                              hipStream_t stream) {
  (void)in_sizes; (void)n_in; (void)out_size;
  if (ws_size < WS_NEED) return;

  const float* img    = (const float*)d_in[0];
  const int*   text   = (const int*)  d_in[1];
  const float* emb    = (const float*)d_in[2];
  const float* W_proj = (const float*)d_in[3];
  const float* b_proj = (const float*)d_in[4];
  const float* W_ih   = (const float*)d_in[5];
  const float* W_hh   = (const float*)d_in[6];
  const float* b_ih   = (const float*)d_in[7];
  const float* b_hh   = (const float*)d_in[8];
  const float* W_out  = (const float*)d_in[9];
  const float* b_out  = (const float*)d_in[10];
  float* out = (float*)d_out;
  char* ws = (char*)d_ws;

  short* whh   = (short*)(ws + OFF_WHH);
  short* wproj = (short*)(ws + OFF_WPROJ);
  short* wout  = (short*)(ws + OFF_WOUT);
  short* wih   = (short*)(ws + OFF_WIH);
  short* embbf = (short*)(ws + OFF_EMBBF);
  float* bhn   = (float*)(ws + OFF_BHN);
  float* bproj = (float*)(ws + OFF_BPROJ);
  float* bout  = (float*)(ws + OFF_BOUT);
  float* bcat  = (float*)(ws + OFF_BCAT);
  float* epf   = (float*)(ws + OFF_EP);
  float4* ep4  = (float4*)(ws + OFF_EP);
  short* hs    = (short*)(ws + OFF_HS);
  short* imgbf = (short*)(ws + OFF_IMG);

  prep_kernel<<<512, 256, 0, stream>>>(W_proj, b_proj, W_hh, b_hh, W_ih, b_ih, emb,
                                       W_out, b_out,
                                       whh, wproj, wout, wih, embbf,
                                       bhn, bproj, bout, bcat);
  imgcvt_kernel<<<4096, 256, 0, stream>>>(img, imgbf);

  // EP = emb @ W_ih^T + biases, via MFMA
  embproj_mfma_kernel<<<dim3(4, 6), 256, 0, stream>>>(embbf, wih, bcat, epf);

  // h0 = img @ W_proj^T + b_proj  -> hs[0] (bf16); 64M x 256N tiles
  gemm_kernel<0><<<dim3(128, 2), 256, 0, stream>>>(imgbf, wproj, bproj, nullptr, hs);

  for (int t = 0; t < 14; ++t) {
    const short* Hb = hs + (size_t)t * SLAB;
    short* Ho       = hs + (size_t)(t + 1) * SLAB;
    gate_kernel<<<512, 256, 0, stream>>>(Hb, whh, text, t, ep4, bhn, Ho);
  }

  // preds: b-major M (m = b*14+t), A = hs slab starting at t=1; 64M tiles
  gemm_kernel<1><<<dim3(1792, 1), 256, 0, stream>>>(hs + (size_t)8192 * 512, wout, bout,
                                                    out, nullptr);
}

// Round 15
// 375.876 us; speedup vs baseline: 1.0518x; 1.0029x over previous
//
#include <hip/hip_runtime.h>
#include <stdint.h>

using bf16x8 = __attribute__((ext_vector_type(8))) __bf16;
using f32x4  = __attribute__((ext_vector_type(4))) float;

#define AS1 __attribute__((address_space(1)))
#define AS3 __attribute__((address_space(3)))

// ---------------- workspace layout (bytes) ----------------
constexpr size_t OFF_WHH   = 0;                                // [1536][512] bf16
constexpr size_t OFF_WPROJ = OFF_WHH   + (size_t)1536*512*2;   // [512][512] bf16
constexpr size_t OFF_WOUT  = OFF_WPROJ + (size_t)512*512*2;    // [256][512] bf16 (padded)
constexpr size_t OFF_WIH   = OFF_WOUT  + (size_t)256*512*2;    // [1536][256] bf16
constexpr size_t OFF_EMBBF = OFF_WIH   + (size_t)1536*256*2;   // [256][256] bf16 (padded)
constexpr size_t OFF_BHN   = OFF_EMBBF + (size_t)256*256*2;    // [512] f32
constexpr size_t OFF_BPROJ = OFF_BHN   + 2048;
constexpr size_t OFF_BOUT  = OFF_BPROJ + 2048;                 // [256] f32 (padded)
constexpr size_t OFF_BCAT  = OFF_BOUT  + 1024;                 // [1536] f32 gate biases
constexpr size_t OFF_EP    = OFF_BCAT  + 1536*4;               // EP4 [193][512] float4 (r,z,n,-)
constexpr size_t OFF_HS    = OFF_EP    + (size_t)193*512*16;   // [15][8192][512] bf16
constexpr size_t OFF_IMG   = OFF_HS    + (size_t)15*8192*512*2;// [8192][512] bf16
constexpr size_t WS_NEED   = OFF_IMG   + (size_t)8192*512*2;   // ~139 MB

constexpr size_t SLAB = (size_t)8192 * 512;

// ---------------- helpers ----------------
__device__ __forceinline__ short f2bf(float f) {
  union { float f; unsigned u; } v; v.f = f;
  unsigned u = v.u;
  u += 0x7FFFu + ((u >> 16) & 1u);   // RNE
  return (short)(u >> 16);
}
__device__ __forceinline__ float bf2f(short s) {
  union { float f; unsigned u; } v; v.u = ((unsigned)(unsigned short)s) << 16;
  return v.f;
}
__device__ __forceinline__ float sigm(float x) { return 1.f / (1.f + __expf(-x)); }
__device__ __forceinline__ float tanh_fast(float x) {
  x = fminf(fmaxf(x, -15.f), 15.f);
  float e = __expf(-2.f * x);
  return (1.f - e) / (1.f + e);
}

// Stage ROWS x 64(bf16) tile: linear LDS dest, XOR-swizzled per-lane global source
// (rule #21: linear dest + inverse-swz source + swz on read).
template<int ROWS, int WAVES>
__device__ __forceinline__ void stage_tile(const short* __restrict__ src, size_t row0,
                                           int stride, int k0, char* lds, int tid) {
  const int w = tid >> 6;
  const int lane = tid & 63;
#pragma unroll
  for (int s = 0; s < ROWS / (8 * WAVES); ++s) {
    const int rowbase = s * (8 * WAVES) + w * 8;   // wave-uniform
    const int row = rowbase + (lane >> 3);
    const int colE = ((lane & 7) ^ (row & 7)) * 8; // pre-swizzled source column
    const short* g = src + (row0 + (size_t)row) * (size_t)stride + k0 + colE;
    __builtin_amdgcn_global_load_lds((const AS1 int*)g, (AS3 int*)(lds + rowbase * 128),
                                     16, 0, 0);
  }
}

// Read a 16x32 MFMA fragment (8 bf16/lane) with the matching XOR swizzle.
__device__ __forceinline__ bf16x8 read_frag(const char* lds, int row, int ks, int lane) {
  const int kb = ks * 64 + ((lane >> 4) << 4);
  return *(const bf16x8*)(lds + row * 128 + (kb ^ ((row & 7) << 4)));
}

// ---------------- fused prep: img->bf16 (blocks 0..4095) + weight/bias pack (4096..4607) ----
__global__ void prep_kernel(const float* __restrict__ img, short* __restrict__ imgbf,
                            const float* __restrict__ W_proj, const float* __restrict__ b_proj,
                            const float* __restrict__ W_hh, const float* __restrict__ b_hh,
                            const float* __restrict__ W_ih, const float* __restrict__ b_ih,
                            const float* __restrict__ emb,
                            const float* __restrict__ W_out, const float* __restrict__ b_out,
                            short* __restrict__ whh, short* __restrict__ wproj,
                            short* __restrict__ wout, short* __restrict__ wih,
                            short* __restrict__ embbf,
                            float* __restrict__ bhn, float* __restrict__ bproj,
                            float* __restrict__ bout, float* __restrict__ bcat) {
  if (blockIdx.x < 4096) {   // img -> bf16, vectorized: 4096*256 threads x 4 floats
    const int i = blockIdx.x * blockDim.x + threadIdx.x;
    const float4 v = *(const float4*)(img + (size_t)i * 4);
    short4 o; o.x = f2bf(v.x); o.y = f2bf(v.y); o.z = f2bf(v.z); o.w = f2bf(v.w);
    *(short4*)(imgbf + (size_t)i * 4) = o;
    return;
  }
  const int total = 1536*512 + 512*512 + 256*512 + 1536*256 + 256*256 + 512 + 512 + 256 + 1536;
  const int stride = 512 * blockDim.x;
  for (int i = (blockIdx.x - 4096) * blockDim.x + threadIdx.x; i < total; i += stride) {
    int j = i;
    if (j < 1536*512) { whh[j] = f2bf(W_hh[j]); continue; }
    j -= 1536*512;
    if (j < 512*512) { wproj[j] = f2bf(W_proj[j]); continue; }
    j -= 512*512;
    if (j < 256*512) {
      int r = j / 512, c = j % 512;
      wout[j] = f2bf(r < 193 ? W_out[r*512 + c] : 0.f);
      continue;
    }
    j -= 256*512;
    if (j < 1536*256) { wih[j] = f2bf(W_ih[j]); continue; }
    j -= 1536*256;
    if (j < 256*256) {
      int r = j >> 8, c = j & 255;
      embbf[j] = f2bf(r < 193 ? emb[r*256 + c] : 0.f);
      continue;
    }
    j -= 256*256;
    if (j < 512) { bhn[j] = b_hh[1024 + j]; continue; }
    j -= 512;
    if (j < 512) { bproj[j] = b_proj[j]; continue; }
    j -= 512;
    if (j < 256) { bout[j] = (j < 193) ? b_out[j] : 0.f; continue; }
    j -= 256;
    bcat[j] = b_ih[j] + (j < 1024 ? b_hh[j] : 0.f);
  }
}

// ---------------- EP via MFMA: EP[256pad x 1536] = embbf @ wih^T + bcat ----------------
// 64M x 256N tile, K=256 (4 iters), grid (4,6). Writes component c>>9 of ep4[v][c&511].
__global__ __launch_bounds__(256, 4)
void embproj_mfma_kernel(const short* __restrict__ embbf, const short* __restrict__ wih,
                         const float* __restrict__ bcat, float* __restrict__ ep) {
  __shared__ __align__(16) char smem[40960];   // A 8K + B 32K
  char* ldsA = smem;
  char* ldsB = smem + 8192;
  const int tid = threadIdx.x;
  const int lane = tid & 63;
  const int w = tid >> 6;
  const int wr = w >> 1, wc = w & 1;   // wave-tile 32M x 128N
  const unsigned m0 = blockIdx.x * 64;
  const int j0 = blockIdx.y * 256;

  f32x4 acc[2][8];
#pragma unroll
  for (int a = 0; a < 2; ++a)
#pragma unroll
    for (int b = 0; b < 8; ++b) acc[a][b] = f32x4{0.f, 0.f, 0.f, 0.f};

  for (int it = 0; it < 4; ++it) {
    const int k0 = it * 64;
    __syncthreads();
    stage_tile<64, 4>(embbf, m0, 256, k0, ldsA, tid);
    stage_tile<256, 4>(wih, (size_t)j0, 256, k0, ldsB, tid);
    __syncthreads();
#pragma unroll
    for (int ks = 0; ks < 2; ++ks) {
      bf16x8 af[2];
#pragma unroll
      for (int mi = 0; mi < 2; ++mi)
        af[mi] = read_frag(ldsA, wr*32 + mi*16 + (lane & 15), ks, lane);
#pragma unroll
      for (int ji = 0; ji < 8; ++ji) {
        bf16x8 bfm = read_frag(ldsB, wc*128 + ji*16 + (lane & 15), ks, lane);
#pragma unroll
        for (int mi = 0; mi < 2; ++mi)
          acc[mi][ji] = __builtin_amdgcn_mfma_f32_16x16x32_bf16(af[mi], bfm, acc[mi][ji], 0, 0, 0);
      }
    }
  }
#pragma unroll
  for (int ji = 0; ji < 8; ++ji) {
    const int c = j0 + wc*128 + ji*16 + (lane & 15);
    const int gate = c >> 9, jj = c & 511;
    const float bc = bcat[c];
#pragma unroll
    for (int mi = 0; mi < 2; ++mi) {
#pragma unroll
      for (int i = 0; i < 4; ++i) {
        const unsigned v = m0 + wr*32 + mi*16 + ((lane >> 4) * 4) + i;
        if (v < 193) ep[((size_t)v * 512 + jj) * 4 + gate] = acc[mi][ji][i] + bc;
      }
    }
  }
}

// ---------------- GEMM, 4 waves (2x2), 64M x 256N tile, K=512, 4 blocks/CU ----------------
// MODE 0: h0 projection. A=imgbf (linear rows), write bf16 hs[0][m][j].
// MODE 1: vocab out. M is b-major (m = b*14 + t); A row = hs1[t*8192 + b];
//         writes f32 out[m*193 + j] (fully contiguous across the tile).
template<int MODE>
__global__ __launch_bounds__(256, 4)
void gemm_kernel(const short* __restrict__ A, const short* __restrict__ Bw,
                 const float* __restrict__ bias, float* __restrict__ out_f,
                 short* __restrict__ out_bf) {
  __shared__ __align__(16) char smem[40960];   // A 8K + B 32K  (x4 blocks/CU = 160K)
  char* ldsA = smem;
  char* ldsB = smem + 8192;
  const int tid = threadIdx.x;
  const int lane = tid & 63;
  const int w = tid >> 6;
  const int wr = w >> 1, wc = w & 1;   // 2x2 wave grid, wave-tile 32M x 128N
  const unsigned m0 = blockIdx.x * 64;
  const int j0 = blockIdx.y * 256;

  f32x4 acc[2][8];
#pragma unroll
  for (int a = 0; a < 2; ++a)
#pragma unroll
    for (int b = 0; b < 8; ++b) acc[a][b] = f32x4{0.f, 0.f, 0.f, 0.f};

  for (int it = 0; it < 8; ++it) {
    const int k0 = it * 64;
    __syncthreads();
    if (MODE == 0) {
      stage_tile<64, 4>(A, m0, 512, k0, ldsA, tid);
    } else {
      // b-major A rows: row r -> m=m0+r -> (b=m/14, t=m%14) -> hs1[t*8192+b]
#pragma unroll
      for (int s = 0; s < 2; ++s) {
        const int rowbase = s * 32 + w * 8;
        const int row = rowbase + (lane >> 3);
        const unsigned m = m0 + row;
        const unsigned b = m / 14u, t = m - b * 14u;
        const int colE = ((lane & 7) ^ (row & 7)) * 8;
        const short* g = A + ((size_t)t * 8192 + b) * 512 + k0 + colE;
        __builtin_amdgcn_global_load_lds((const AS1 int*)g, (AS3 int*)(ldsA + rowbase * 128),
                                         16, 0, 0);
      }
    }
    stage_tile<256, 4>(Bw, (size_t)j0, 512, k0, ldsB, tid);
    __syncthreads();
#pragma unroll
    for (int ks = 0; ks < 2; ++ks) {
      bf16x8 af[2];
#pragma unroll
      for (int mi = 0; mi < 2; ++mi)
        af[mi] = read_frag(ldsA, wr*32 + mi*16 + (lane & 15), ks, lane);
#pragma unroll
      for (int ji = 0; ji < 8; ++ji) {
        bf16x8 bfm = read_frag(ldsB, wc*128 + ji*16 + (lane & 15), ks, lane);
#pragma unroll
        for (int mi = 0; mi < 2; ++mi)
          acc[mi][ji] = __builtin_amdgcn_mfma_f32_16x16x32_bf16(af[mi], bfm, acc[mi][ji], 0, 0, 0);
      }
    }
  }
#pragma unroll
  for (int ji = 0; ji < 8; ++ji) {
    const int j = j0 + wc*128 + ji*16 + (lane & 15);
    const float bj = bias[j];
#pragma unroll
    for (int mi = 0; mi < 2; ++mi) {
#pragma unroll
      for (int i = 0; i < 4; ++i) {
        const size_t m = m0 + wr*32 + mi*16 + ((lane >> 4) * 4) + i;
        const float v = acc[mi][ji][i] + bj;
        if (MODE == 0) {
          out_bf[m * 512 + j] = f2bf(v);
        } else {
          if (j < 193) out_f[m * 193 + j] = v;   // m is b-major bt index: contiguous
        }
      }
    }
  }
}

// ---------------- fused GRU step: gh = h @ W_hh^T, BK=128, XCD-swizzled 1-D grid ----
// Grid 512 blocks; decode so each XCD (id&7, round-robin dispatch) owns
// 8 consecutive m-tiles x all 8 j-tiles -> per-XCD L2 working set = 1MB h + 1.5MB whh.
// LDS: A0|A1 (16K each) + B0|B1 (24K each) = 80K; 2 blocks/CU = 160K exact.
// toks + h_old prefetched into registers before the K-loop (latency hides under GEMM).
__global__ __launch_bounds__(256, 2)
void gate_kernel(const short* __restrict__ Hbf, const short* __restrict__ whh,
                 const int* __restrict__ text, const int t,
                 const float4* __restrict__ ep4, const float* __restrict__ bhn,
                 short* __restrict__ hs_out) {
  __shared__ __align__(16) char smem[81920];
  char* ldsA0 = smem;                // [128][64] k-half 0
  char* ldsA1 = smem + 16384;        // [128][64] k-half 1
  char* ldsB0 = smem + 32768;        // 3 x [64][64] k-half 0
  char* ldsB1 = smem + 57344;        // 3 x [64][64] k-half 1
  const int tid = threadIdx.x;
  const int lane = tid & 63;
  const int w = tid >> 6;
  const int wr = w >> 1, wc = w & 1;   // wave-tile 64M x 32N
  const unsigned raw = blockIdx.x;
  const unsigned xcd = raw & 7, slot = raw >> 3;
  const unsigned mt = xcd * 8 + (slot & 7), jt = slot >> 3;
  const size_t m0 = (size_t)mt * 128;
  const int j0 = jt * 64;

  int jj[2];
#pragma unroll
  for (int ji = 0; ji < 2; ++ji) jj[ji] = j0 + wc*32 + ji*16 + (lane & 15);

  // prefetch tokens + h_old (latency hides under the K-loop)
  int toks[4][4];
  short holds[4][4][2];
#pragma unroll
  for (int mi = 0; mi < 4; ++mi)
#pragma unroll
    for (int i = 0; i < 4; ++i) {
      const size_t m = m0 + wr*64 + mi*16 + ((lane >> 4) * 4) + i;
      toks[mi][i] = text[m * 15 + t];
#pragma unroll
      for (int ji = 0; ji < 2; ++ji) holds[mi][i][ji] = Hbf[m * 512 + jj[ji]];
    }

  f32x4 acc_r[4][2], acc_z[4][2], acc_hn[4][2];
#pragma unroll
  for (int a = 0; a < 4; ++a)
#pragma unroll
    for (int b = 0; b < 2; ++b) {
      acc_r[a][b] = f32x4{0.f, 0.f, 0.f, 0.f};
      acc_z[a][b] = f32x4{0.f, 0.f, 0.f, 0.f};
      acc_hn[a][b] = f32x4{0.f, 0.f, 0.f, 0.f};
    }

  for (int it = 0; it < 4; ++it) {
    const int k0 = it * 128;
    __syncthreads();
    stage_tile<128, 4>(Hbf, m0, 512, k0, ldsA0, tid);
    stage_tile<128, 4>(Hbf, m0, 512, k0 + 64, ldsA1, tid);
#pragma unroll
    for (int g = 0; g < 3; ++g) {
      stage_tile<64, 4>(whh, (size_t)(g * 512 + j0), 512, k0,      ldsB0 + g * 8192, tid);
      stage_tile<64, 4>(whh, (size_t)(g * 512 + j0), 512, k0 + 64, ldsB1 + g * 8192, tid);
    }
    __syncthreads();
#pragma unroll
    for (int half = 0; half < 2; ++half) {
      const char* lA = half ? ldsA1 : ldsA0;
      const char* lB = half ? ldsB1 : ldsB0;
#pragma unroll
      for (int ks = 0; ks < 2; ++ks) {
        bf16x8 af[4];
#pragma unroll
        for (int mi = 0; mi < 4; ++mi)
          af[mi] = read_frag(lA, wr*64 + mi*16 + (lane & 15), ks, lane);
#pragma unroll
        for (int ji = 0; ji < 2; ++ji) {
          const int nb = wc*32 + ji*16 + (lane & 15);
          bf16x8 b_r = read_frag(lB,         nb, ks, lane);
          bf16x8 b_z = read_frag(lB + 8192,  nb, ks, lane);
          bf16x8 b_n = read_frag(lB + 16384, nb, ks, lane);
#pragma unroll
          for (int mi = 0; mi < 4; ++mi) {
            acc_r[mi][ji]  = __builtin_amdgcn_mfma_f32_16x16x32_bf16(af[mi], b_r, acc_r[mi][ji], 0, 0, 0);
            acc_z[mi][ji]  = __builtin_amdgcn_mfma_f32_16x16x32_bf16(af[mi], b_z, acc_z[mi][ji], 0, 0, 0);
            acc_hn[mi][ji] = __builtin_amdgcn_mfma_f32_16x16x32_bf16(af[mi], b_n, acc_hn[mi][ji], 0, 0, 0);
          }
        }
      }
    }
  }
  // epilogue: gather EP4[token] + gate math + h update
#pragma unroll
  for (int ji = 0; ji < 2; ++ji) {
    const int j = jj[ji];
    const float vbhn = bhn[j];
#pragma unroll
    for (int mi = 0; mi < 4; ++mi) {
#pragma unroll
      for (int i = 0; i < 4; ++i) {
        const size_t m = m0 + wr*64 + mi*16 + ((lane >> 4) * 4) + i;
        const float4 e = ep4[(size_t)toks[mi][i] * 512 + j];
        const float r = sigm(acc_r[mi][ji][i] + e.x);
        const float z = sigm(acc_z[mi][ji][i] + e.y);
        const float n = tanh_fast(e.z + r * (acc_hn[mi][ji][i] + vbhn));
        const float hold = bf2f(holds[mi][i][ji]);
        hs_out[m * 512 + j] = f2bf((1.f - z) * n + z * hold);
      }
    }
  }
}

// ---------------- launch ----------------
extern "C" void kernel_launch(void* const* d_in, const int* in_sizes, int n_in,
                              void* d_out, int out_size, void* d_ws, size_t ws_size,
                              hipStream_t stream) {
  (void)in_sizes; (void)n_in; (void)out_size;
  if (ws_size < WS_NEED) return;

  const float* img    = (const float*)d_in[0];
  const int*   text   = (const int*)  d_in[1];
  const float* emb    = (const float*)d_in[2];
  const float* W_proj = (const float*)d_in[3];
  const float* b_proj = (const float*)d_in[4];
  const float* W_ih   = (const float*)d_in[5];
  const float* W_hh   = (const float*)d_in[6];
  const float* b_ih   = (const float*)d_in[7];
  const float* b_hh   = (const float*)d_in[8];
  const float* W_out  = (const float*)d_in[9];
  const float* b_out  = (const float*)d_in[10];
  float* out = (float*)d_out;
  char* ws = (char*)d_ws;

  short* whh   = (short*)(ws + OFF_WHH);
  short* wproj = (short*)(ws + OFF_WPROJ);
  short* wout  = (short*)(ws + OFF_WOUT);
  short* wih   = (short*)(ws + OFF_WIH);
  short* embbf = (short*)(ws + OFF_EMBBF);
  float* bhn   = (float*)(ws + OFF_BHN);
  float* bproj = (float*)(ws + OFF_BPROJ);
  float* bout  = (float*)(ws + OFF_BOUT);
  float* bcat  = (float*)(ws + OFF_BCAT);
  float* epf   = (float*)(ws + OFF_EP);
  float4* ep4  = (float4*)(ws + OFF_EP);
  short* hs    = (short*)(ws + OFF_HS);
  short* imgbf = (short*)(ws + OFF_IMG);

  prep_kernel<<<4608, 256, 0, stream>>>(img, imgbf,
                                        W_proj, b_proj, W_hh, b_hh, W_ih, b_ih, emb,
                                        W_out, b_out,
                                        whh, wproj, wout, wih, embbf,
                                        bhn, bproj, bout, bcat);

  // EP = emb @ W_ih^T + biases, via MFMA
  embproj_mfma_kernel<<<dim3(4, 6), 256, 0, stream>>>(embbf, wih, bcat, epf);

  // h0 = img @ W_proj^T + b_proj  -> hs[0] (bf16); 64M x 256N tiles
  gemm_kernel<0><<<dim3(128, 2), 256, 0, stream>>>(imgbf, wproj, bproj, nullptr, hs);

  for (int t = 0; t < 14; ++t) {
    const short* Hb = hs + (size_t)t * SLAB;
    short* Ho       = hs + (size_t)(t + 1) * SLAB;
    gate_kernel<<<512, 256, 0, stream>>>(Hb, whh, text, t, ep4, bhn, Ho);
  }

  // preds: b-major M (m = b*14+t), A = hs slab starting at t=1; 64M tiles
  gemm_kernel<1><<<dim3(1792, 1), 256, 0, stream>>>(hs + (size_t)8192 * 512, wout, bout,
                                                    out, nullptr);
}